// Round 9
// baseline (298.835 us; speedup 1.0000x reference)
//
#include <hip/hip_runtime.h>
#include <hip/hip_bf16.h>

typedef float  f32x4v __attribute__((ext_vector_type(4)));
typedef short  bf16x8 __attribute__((ext_vector_type(8)));

#define NFRAG   26
#define TB_F32  512                            // 16 tables x 32 f32
#define FRG_U16 (NFRAG*512)                    // 26 frags x 64 lanes x 8 bf16
#define SHARE_BYTES (TB_F32*4 + FRG_U16*2)     // 28672 B staged to LDS
#define SHARE_U4 (SHARE_BYTES/16)              // 1792 uint4
#define WC_OFF 7168                            // WC scratch offset in WS floats

#define BLK 256
#define COPY_BLOCKS 256
#define EDGE_BLOCKS 1024
#define GRID (COPY_BLOCKS + EDGE_BLOCKS)       // 1280 = 5 blocks/CU resident
#define EDGE_WAVES (EDGE_BLOCKS * 4)           // 4096

#define MFMA(a,b,c) __builtin_amdgcn_mfma_f32_16x16x32_bf16(a,b,c,0,0,0)

__device__ __forceinline__ float sigf(float v) { return 1.0f / (1.0f + __expf(-v)); }
__device__ __forceinline__ float tanhf_fast(float v) {
    float a = fabsf(v);
    float t = __expf(-2.0f * a);
    float r = (1.0f - t) / (1.0f + t);
    return v < 0.0f ? -r : r;
}
__device__ __forceinline__ unsigned pk(float a, float b) {   // bf16(a) lo | bf16(b) hi
    union { __hip_bfloat162 h; unsigned u; } c;
    c.h = __float22bfloat162_rn(make_float2(a, b));
    return c.u;
}

union FragU { uint4 u4; bf16x8 s8; unsigned u[4]; };

__device__ __forceinline__ bf16x8 ldfrag(const unsigned short* frg, int idx_u16) {
    FragU c; c.u4 = *(const uint4*)(frg + idx_u16); return c.s8;
}
__device__ __forceinline__ f32x4v tbl(const float* tb, int idx_f32) {
    return *(const f32x4v*)(tb + idx_f32);
}
// In-register D->B relayout: lane (eI,g) holds D rows 4g..4g+3 of both 16-row
// tiles; the consumer A-fragments are packed with k-order m(k) so these 8
// values ARE the lane's B fragment. Zero cross-lane ops, zero LDS.
__device__ __forceinline__ bf16x8 relayout_reg(f32x4v h0, f32x4v h1) {
    FragU c;
    c.u[0] = pk(h0[0], h0[1]); c.u[1] = pk(h0[2], h0[3]);
    c.u[2] = pk(h1[0], h1[1]); c.u[3] = pk(h1[2], h1[3]);
    return c.s8;
}

__global__ void winner_k(const int* __restrict__ dst_ids, int* __restrict__ winner, int E) {
    int e = blockIdx.x * 256 + threadIdx.x;
    if (e < E) atomicMax(winner + dst_ids[e], e + 1);
}

__global__ void prep_k(const float* __restrict__ msg_W1, const float* __restrict__ msg_b1,
                       const float* __restrict__ msg_W2, const float* __restrict__ msg_b2,
                       const float* __restrict__ w_ih, const float* __restrict__ b_ih,
                       const float* __restrict__ w_hh, const float* __restrict__ b_hh,
                       const float* __restrict__ Wv, const float* __restrict__ bv,
                       const float* __restrict__ Wo, const float* __restrict__ bo,
                       const float* __restrict__ emb_W1, const float* __restrict__ emb_b1,
                       const float* __restrict__ emb_W2, const float* __restrict__ emb_b2,
                       const float* __restrict__ cls_W1, const float* __restrict__ cls_b1,
                       const float* __restrict__ cls_W2, float* __restrict__ WSf) {
    int t = threadIdx.x;  // one block, 256 threads
    float* tb = WSf;
    unsigned short* frg = (unsigned short*)(WSf + TB_F32);
    float* WC = WSf + WC_OFF;  // [32][32] folded Wo@Wv
    if (t < 32) {
        int j = t;
        tb[0*32+j]  = msg_b1[j];
        tb[1*32+j]  = msg_W1[j*67+64];
        tb[2*32+j]  = msg_W1[j*67+65];
        tb[3*32+j]  = msg_W1[j*67+66];
        tb[4*32+j]  = msg_b2[j];
        tb[5*32+j]  = b_ih[32+j] + b_hh[32+j];     // z bias
        tb[6*32+j]  = b_ih[j] + b_hh[j];           // r bias
        tb[7*32+j]  = b_hh[64+j];                  // h_n bias
        tb[8*32+j]  = b_ih[64+j];                  // i_n bias
        float a = bo[j];
        for (int o = 0; o < 32; ++o) a += Wo[j*32+o] * bv[o];
        tb[9*32+j]  = a;                           // folded attn bias
        tb[10*32+j] = emb_b1[j];
        tb[11*32+j] = emb_W1[j*34+32];
        tb[12*32+j] = emb_W1[j*34+33];
        tb[13*32+j] = emb_b2[j];
        tb[14*32+j] = cls_b1[j];
        tb[15*32+j] = cls_W2[j];
    }
    for (int i = t; i < 1024; i += 256) {
        int j = i >> 5, k = i & 31;
        float a = 0.0f;
        for (int o = 0; o < 32; ++o) a += Wo[j*32+o] * Wv[o*32+k];
        WC[i] = a;
    }
    __syncthreads();
    // A-fragment pack: frag f, lane l, elem i -> W[j0 + (l&15)][k0 + kidx]
    // where kidx = kb (natural) or m(kb) (consumers of relayout_reg output).
    for (int idx = t; idx < NFRAG * 512; idx += 256) {
        int f = idx >> 9, l = (idx >> 3) & 63, i = idx & 7;
        int r = l & 15, kb = ((l >> 4) << 3) + i;
        const float* P; int j0 = 0, k0 = 0, ld = 32;
        bool mapped = false;  // consumes a relayout_reg B fragment
        switch (f) {
            case 0:  P = msg_W1; j0 = 0;  k0 = 0;  ld = 67; break;
            case 1:  P = msg_W1; j0 = 0;  k0 = 32; ld = 67; break;
            case 2:  P = msg_W1; j0 = 16; k0 = 0;  ld = 67; break;
            case 3:  P = msg_W1; j0 = 16; k0 = 32; ld = 67; break;
            case 4:  P = msg_W2; j0 = 0;  mapped = true; break;
            case 5:  P = msg_W2; j0 = 16; mapped = true; break;
            case 6:  P = w_ih;   j0 = 32; mapped = true; break;   // z ih
            case 7:  P = w_hh;   j0 = 32; break;                  // z hh
            case 8:  P = w_ih;   j0 = 48; mapped = true; break;
            case 9:  P = w_hh;   j0 = 48; break;
            case 10: P = w_ih;   j0 = 0;  mapped = true; break;   // r ih
            case 11: P = w_hh;   j0 = 0;  break;
            case 12: P = w_ih;   j0 = 16; mapped = true; break;
            case 13: P = w_hh;   j0 = 16; break;
            case 14: P = w_hh;   j0 = 64; break;                  // n hh
            case 15: P = w_hh;   j0 = 80; break;
            case 16: P = w_ih;   j0 = 64; mapped = true; break;   // n ih
            case 17: P = w_ih;   j0 = 80; mapped = true; break;
            case 18: P = WC;     j0 = 0;  break;                  // folded attn
            case 19: P = WC;     j0 = 16; break;
            case 20: P = emb_W1; j0 = 0;  ld = 34; mapped = true; break;
            case 21: P = emb_W1; j0 = 16; ld = 34; mapped = true; break;
            case 22: P = emb_W2; j0 = 0;  mapped = true; break;
            case 23: P = emb_W2; j0 = 16; mapped = true; break;
            case 24: P = cls_W1; j0 = 0;  mapped = true; break;
            default: P = cls_W1; j0 = 16; mapped = true; break;
        }
        int kidx = kb;
        if (mapped) kidx = 16 * ((kb >> 2) & 1) + 4 * (kb >> 3) + (kb & 3);
        __hip_bfloat16 hv = __float2bfloat16(P[(j0 + r) * ld + k0 + kidx]);
        frg[idx] = *(unsigned short*)&hv;
    }
}

__device__ __forceinline__ void compute16(
    int grp, int E, int eI, int g, int lane,
    int e, int dst, int winv, float2 ef, float dtv,
    f32x4v sa, f32x4v sb, f32x4v da, f32x4v db, f32x4v t0, f32x4v t1,
    const float* tb, const unsigned short* frg, float clsb2,
    float* __restrict__ probs, float* __restrict__ out_mem) {
    int ob = 0, tbo = 0;
    asm volatile("" : "+v"(ob), "+v"(tbo));  // block LICM of LDS frag/table reads

    FragU Bs, Bd;
    Bs.u[0] = pk(sa[0], sa[1]); Bs.u[1] = pk(sa[2], sa[3]);
    Bs.u[2] = pk(sb[0], sb[1]); Bs.u[3] = pk(sb[2], sb[3]);
    Bd.u[0] = pk(da[0], da[1]); Bd.u[1] = pk(da[2], da[3]);
    Bd.u[2] = pk(db[0], db[1]); Bd.u[3] = pk(db[2], db[3]);
    f32x4v dmt[2]; dmt[0] = t0; dmt[1] = t1;   // dst mem in D layout (exact f32)

    // ---- msg1: relu(W1 @ [sm, dm, ef, dt] + b1) ----
    f32x4v h[2];
#pragma unroll
    for (int jt = 0; jt < 2; ++jt) {
        f32x4v b1v = tbl(tb, 0*32 + jt*16 + 4*g + tbo);
        f32x4v w64 = tbl(tb, 1*32 + jt*16 + 4*g + tbo);
        f32x4v w65 = tbl(tb, 2*32 + jt*16 + 4*g + tbo);
        f32x4v w66 = tbl(tb, 3*32 + jt*16 + 4*g + tbo);
        f32x4v c;
#pragma unroll
        for (int i = 0; i < 4; ++i)
            c[i] = b1v[i] + ef.x * w64[i] + ef.y * w65[i] + dtv * w66[i];
        c = MFMA(ldfrag(frg, (jt*2+1)*512 + lane*8 + ob), Bd.s8, c);
        c = MFMA(ldfrag(frg, (jt*2+0)*512 + lane*8 + ob), Bs.s8, c);
#pragma unroll
        for (int i = 0; i < 4; ++i) c[i] = fmaxf(c[i], 0.0f);
        h[jt] = c;
    }
    bf16x8 Bh = relayout_reg(h[0], h[1]);

    // ---- msg2 ----
    f32x4v m[2];
#pragma unroll
    for (int jt = 0; jt < 2; ++jt)
        m[jt] = MFMA(ldfrag(frg, (4+jt)*512 + lane*8 + ob), Bh,
                     tbl(tb, 4*32 + jt*16 + 4*g + tbo));
    bf16x8 Bm = relayout_reg(m[0], m[1]);

    // ---- GRU ----
    f32x4v zz[2], uu[2];
#pragma unroll
    for (int jt = 0; jt < 2; ++jt) {
        f32x4v c = tbl(tb, 5*32 + jt*16 + 4*g + tbo);
        c = MFMA(ldfrag(frg, (7+2*jt)*512 + lane*8 + ob), Bd.s8, c);
        c = MFMA(ldfrag(frg, (6+2*jt)*512 + lane*8 + ob), Bm, c);
#pragma unroll
        for (int i = 0; i < 4; ++i) c[i] = sigf(c[i]);
        zz[jt] = c;
    }
#pragma unroll
    for (int jt = 0; jt < 2; ++jt) {
        f32x4v c = tbl(tb, 6*32 + jt*16 + 4*g + tbo);       // r pre-act
        c = MFMA(ldfrag(frg, (11+2*jt)*512 + lane*8 + ob), Bd.s8, c);
        c = MFMA(ldfrag(frg, (10+2*jt)*512 + lane*8 + ob), Bm, c);
        f32x4v hn = tbl(tb, 7*32 + jt*16 + 4*g + tbo);      // h_n
        hn = MFMA(ldfrag(frg, (14+jt)*512 + lane*8 + ob), Bd.s8, hn);
        f32x4v bin = tbl(tb, 8*32 + jt*16 + 4*g + tbo);
        f32x4v npre;
#pragma unroll
        for (int i = 0; i < 4; ++i) npre[i] = fmaf(sigf(c[i]), hn[i], bin[i]);
        npre = MFMA(ldfrag(frg, (16+jt)*512 + lane*8 + ob), Bm, npre);
#pragma unroll
        for (int i = 0; i < 4; ++i) {
            float n = tanhf_fast(npre[i]);
            uu[jt][i] = n + zz[jt][i] * (dmt[jt][i] - n);
        }
    }
    if (winv == e + 1) {
        f32x4v* orow = (f32x4v*)(out_mem + (size_t)dst * 32);
        orow[g]     = uu[0];
        orow[4 + g] = uu[1];
    }

    // ---- attn (folded) -> emb1 -> emb2 -> cls ----
    f32x4v at[2];
#pragma unroll
    for (int jt = 0; jt < 2; ++jt)
        at[jt] = MFMA(ldfrag(frg, (18+jt)*512 + lane*8 + ob), Bd.s8,
                      tbl(tb, 9*32 + jt*16 + 4*g + tbo));
    bf16x8 Ba = relayout_reg(at[0], at[1]);
    f32x4v e1v[2];
#pragma unroll
    for (int jt = 0; jt < 2; ++jt) {
        f32x4v b  = tbl(tb, 10*32 + jt*16 + 4*g + tbo);
        f32x4v wa = tbl(tb, 11*32 + jt*16 + 4*g + tbo);
        f32x4v wb = tbl(tb, 12*32 + jt*16 + 4*g + tbo);
        f32x4v c;
#pragma unroll
        for (int i = 0; i < 4; ++i) c[i] = b[i] + ef.x * wa[i] + ef.y * wb[i];
        c = MFMA(ldfrag(frg, (20+jt)*512 + lane*8 + ob), Ba, c);
#pragma unroll
        for (int i = 0; i < 4; ++i) c[i] = fmaxf(c[i], 0.0f);
        e1v[jt] = c;
    }
    bf16x8 B1 = relayout_reg(e1v[0], e1v[1]);
    f32x4v e2v[2];
#pragma unroll
    for (int jt = 0; jt < 2; ++jt)
        e2v[jt] = MFMA(ldfrag(frg, (22+jt)*512 + lane*8 + ob), B1,
                       tbl(tb, 13*32 + jt*16 + 4*g + tbo));
    bf16x8 B2 = relayout_reg(e2v[0], e2v[1]);
    float part = 0.0f;
#pragma unroll
    for (int jt = 0; jt < 2; ++jt) {
        f32x4v c = MFMA(ldfrag(frg, (24+jt)*512 + lane*8 + ob), B2,
                        tbl(tb, 14*32 + jt*16 + 4*g + tbo));
        f32x4v w2 = tbl(tb, 15*32 + jt*16 + 4*g + tbo);
#pragma unroll
        for (int i = 0; i < 4; ++i) part = fmaf(fmaxf(c[i], 0.0f), w2[i], part);
    }
    part += __shfl_xor(part, 16);
    part += __shfl_xor(part, 32);
    if (lane < 16) {
        int ee = grp * 16 + eI;
        if (ee < E) probs[ee] = sigf(part + clsb2);
    }
}

__global__ __launch_bounds__(BLK, 5) void tgn_mfma16(
    const int* __restrict__ src_ids, const int* __restrict__ dst_ids,
    const float* __restrict__ edge_feat, const float* __restrict__ delta_t,
    const float* __restrict__ memory, const float* __restrict__ cls_b2,
    const float* __restrict__ WSf, const int* __restrict__ winner,
    float* __restrict__ probs, float* __restrict__ out_mem,
    int E, int N, int ngrp) {
    __shared__ uint4 sbuf[SHARE_U4];
    int bid = blockIdx.x, tid = threadIdx.x;

    if (bid < COPY_BLOCKS) {  // copy workers: non-winner rows -> out_mem
        const f32x4v* m4 = (const f32x4v*)memory;
        f32x4v* o4 = (f32x4v*)out_mem;
        const long S = (long)COPY_BLOCKS * BLK;
        const long total4 = (long)N * 8;
        long i0 = (long)bid * BLK + tid;
        for (; i0 + 3 * S < total4; i0 += 4 * S) {
            long i1 = i0 + S, i2 = i0 + 2 * S, i3 = i0 + 3 * S;
            int w0 = winner[i0 >> 3];
            int w1 = winner[i1 >> 3];
            int w2 = winner[i2 >> 3];
            int w3 = winner[i3 >> 3];
            if (w0 == 0) o4[i0] = m4[i0];
            if (w1 == 0) o4[i1] = m4[i1];
            if (w2 == 0) o4[i2] = m4[i2];
            if (w3 == 0) o4[i3] = m4[i3];
        }
        for (; i0 < total4; i0 += S) {
            if (winner[i0 >> 3] == 0) o4[i0] = m4[i0];
        }
        return;
    }

    {   // stage tables + A-fragments into LDS
        const uint4* s = (const uint4*)WSf;
        for (int i = tid; i < SHARE_U4; i += BLK) sbuf[i] = s[i];
    }
    __syncthreads();
    const float* tb = (const float*)sbuf;
    const unsigned short* frg = (const unsigned short*)((const float*)sbuf + TB_F32);
    int wv = tid >> 6, lane = tid & 63;
    int eI = lane & 15, g = lane >> 4;
    int ewid = (bid - COPY_BLOCKS) * 4 + wv;
    float clsb2 = cls_b2[0];

#define PREF(P, G) do {                                                              \
    int ee = (G) * 16 + eI; if (ee >= E) ee = E - 1;                                 \
    e##P = ee;                                                                       \
    int sid = src_ids[ee]; dst##P = dst_ids[ee];                                     \
    ef##P = ((const float2*)edge_feat)[ee]; dt##P = delta_t[ee];                     \
    win##P = winner[dst##P];                                                         \
    const f32x4v* sp_ = (const f32x4v*)(memory + (size_t)sid * 32);                  \
    const f32x4v* dp_ = (const f32x4v*)(memory + (size_t)dst##P * 32);               \
    S##P##a = sp_[2*g]; S##P##b = sp_[2*g+1];                                        \
    D##P##a = dp_[2*g]; D##P##b = dp_[2*g+1];                                        \
    T##P##0 = dp_[g];   T##P##1 = dp_[4+g];                                          \
} while (0)

    int g0 = ewid;
    if (g0 < ngrp) {
        int eA, dstA, winA; float2 efA; float dtA;
        f32x4v SAa, SAb, DAa, DAb, TA0, TA1;
        int eB, dstB, winB; float2 efB; float dtB;
        f32x4v SBa, SBb, DBa, DBb, TB0, TB1;
        PREF(A, g0);
        for (;;) {
            int gn = g0 + EDGE_WAVES;
            { int gp = (gn < ngrp) ? gn : (ngrp - 1); PREF(B, gp); }
            asm volatile("" ::: "memory");   // pin: B's loads may not sink below
            compute16(g0, E, eI, g, lane, eA, dstA, winA, efA, dtA,
                      SAa, SAb, DAa, DAb, TA0, TA1,
                      tb, frg, clsb2, probs, out_mem);
            if (gn >= ngrp) break;
            g0 = gn;
            gn = g0 + EDGE_WAVES;
            { int gp = (gn < ngrp) ? gn : (ngrp - 1); PREF(A, gp); }
            asm volatile("" ::: "memory");
            compute16(g0, E, eI, g, lane, eB, dstB, winB, efB, dtB,
                      SBa, SBb, DBa, DBb, TB0, TB1,
                      tb, frg, clsb2, probs, out_mem);
            if (gn >= ngrp) break;
            g0 = gn;
        }
    }
#undef PREF
}

extern "C" void kernel_launch(void* const* d_in, const int* in_sizes, int n_in,
                              void* d_out, int out_size, void* d_ws, size_t ws_size,
                              hipStream_t stream) {
    const int*   src_ids   = (const int*)d_in[0];
    const int*   dst_ids   = (const int*)d_in[1];
    const float* edge_feat = (const float*)d_in[2];
    const float* delta_t   = (const float*)d_in[3];
    const float* memory    = (const float*)d_in[4];
    const float* msg_W1 = (const float*)d_in[5],  *msg_b1 = (const float*)d_in[6];
    const float* msg_W2 = (const float*)d_in[7],  *msg_b2 = (const float*)d_in[8];
    const float* w_ih   = (const float*)d_in[9],  *b_ih   = (const float*)d_in[10];
    const float* w_hh   = (const float*)d_in[11], *b_hh   = (const float*)d_in[12];
    const float* Wv     = (const float*)d_in[13], *bv     = (const float*)d_in[14];
    const float* Wo     = (const float*)d_in[15], *bo     = (const float*)d_in[16];
    const float* emb_W1 = (const float*)d_in[17], *emb_b1 = (const float*)d_in[18];
    const float* emb_W2 = (const float*)d_in[19], *emb_b2 = (const float*)d_in[20];
    const float* cls_W1 = (const float*)d_in[21], *cls_b1 = (const float*)d_in[22];
    const float* cls_W2 = (const float*)d_in[23], *cls_b2 = (const float*)d_in[24];

    int E = in_sizes[0];
    int N = in_sizes[4] / 32;
    int ngrp = (E + 15) / 16;

    int*   winner = (int*)d_ws;
    float* WSf    = (float*)((char*)d_ws + (size_t)N * sizeof(int));
    float* probs  = (float*)d_out;
    float* outmem = probs + E;

    hipMemsetAsync(winner, 0, (size_t)N * sizeof(int), stream);
    winner_k<<<(E + 255) / 256, 256, 0, stream>>>(dst_ids, winner, E);
    prep_k<<<1, 256, 0, stream>>>(msg_W1, msg_b1, msg_W2, msg_b2,
                                  w_ih, b_ih, w_hh, b_hh,
                                  Wv, bv, Wo, bo,
                                  emb_W1, emb_b1, emb_W2, emb_b2,
                                  cls_W1, cls_b1, cls_W2, WSf);
    tgn_mfma16<<<GRID, BLK, 0, stream>>>(src_ids, dst_ids, edge_feat, delta_t,
                                         memory, cls_b2, WSf, winner,
                                         probs, outmem, E, N, ngrp);
}